// Round 2
// baseline (139.638 us; speedup 1.0000x reference)
//
#include <hip/hip_runtime.h>
#include <hip/hip_bf16.h>
#include <cstdint>
#include <cstddef>

#define A_DIM 128
#define T_DIM 2048
#define F_DIM 128
#define RBF_DIM 16
#define TTILE 32
#define NCHUNK 4

__device__ __forceinline__ float silu_f(float x) {
    return x / (1.0f + __expf(-x));
}

// grid (A/4, 3), block 512. h1/h2 MLP layers for 4 atoms, one output/thread/layer.
__global__ void mlp12_kernel(const float* __restrict__ feat0,
                             const float* __restrict__ w1, const float* __restrict__ b1,
                             const float* __restrict__ w2, const float* __restrict__ b2,
                             float* __restrict__ h2ws) {
    __shared__ float inv_s[4 * F_DIM];
    __shared__ float h_s[4 * F_DIM];
    const int i  = blockIdx.y;
    const int a0 = blockIdx.x * 4;
    const int tid = threadIdx.x;
    const int f  = tid & 127;
    const int la = tid >> 7;

    inv_s[tid] = feat0[(a0 + la) * F_DIM + f];  // feat0 is (A,F,1)
    __syncthreads();

    const float* w1i = w1 + (size_t)i * F_DIM * F_DIM;
    float x = b1[i * F_DIM + f];
    #pragma unroll 8
    for (int k = 0; k < F_DIM; ++k)
        x = fmaf(inv_s[la * F_DIM + k], w1i[k * F_DIM + f], x);
    h_s[tid] = silu_f(x);
    __syncthreads();

    const float* w2i = w2 + (size_t)i * F_DIM * F_DIM;
    float y = b2[i * F_DIM + f];
    #pragma unroll 8
    for (int k = 0; k < F_DIM; ++k)
        y = fmaf(h_s[la * F_DIM + k], w2i[k * F_DIM + f], y);
    h2ws[((size_t)i * A_DIM + a0 + la) * F_DIM + f] = silu_f(y);
}

// grid (A/4, 2, 3), block 256. Layer 3: (4 atoms)x(1024 cols) tile, 4x4 register tile.
__global__ void mlp3_kernel(const float* __restrict__ h2ws,
                            const float* __restrict__ w3, const float* __restrict__ b3,
                            float* __restrict__ rbfws) {
    __shared__ float h2_s[4 * F_DIM];
    const int i  = blockIdx.z;
    const int a0 = blockIdx.x * 4;
    const int c0 = blockIdx.y * 1024;
    const int tid = threadIdx.x;

    for (int j = tid; j < 4 * F_DIM; j += 256)
        h2_s[j] = h2ws[((size_t)i * A_DIM + a0) * F_DIM + j];
    __syncthreads();

    const int c = c0 + tid * 4;
    const float* w3i = w3 + (size_t)i * F_DIM * 2048;
    float val[4][4];
    #pragma unroll
    for (int a = 0; a < 4; ++a) {
        #pragma unroll
        for (int cc = 0; cc < 4; ++cc)
            val[a][cc] = b3[i * 2048 + c + cc];
    }
    for (int k = 0; k < F_DIM; ++k) {
        const float4 w = *reinterpret_cast<const float4*>(&w3i[(size_t)k * 2048 + c]);
        #pragma unroll
        for (int a = 0; a < 4; ++a) {
            const float h = h2_s[a * F_DIM + k];
            val[a][0] = fmaf(h, w.x, val[a][0]);
            val[a][1] = fmaf(h, w.y, val[a][1]);
            val[a][2] = fmaf(h, w.z, val[a][2]);
            val[a][3] = fmaf(h, w.w, val[a][3]);
        }
    }
    const float inv_rbf = 0.25f;  // 1/sqrt(16)
    #pragma unroll
    for (int a = 0; a < 4; ++a) {
        float4 o;
        o.x = val[a][0] * inv_rbf;
        o.y = val[a][1] * inv_rbf;
        o.z = val[a][2] * inv_rbf;
        o.w = val[a][3] * inv_rbf;
        *reinterpret_cast<float4*>(&rbfws[((size_t)i * A_DIM + a0 + a) * 2048 + c]) = o;
    }
}

// grid (T/32, A/4), block 128 (thread = one f). Factorized einsum, acc into sparse (T,F).
// t-loop FULLY unrolled so acc[]/rb[] are statically indexed -> registers, not scratch.
__global__ void __launch_bounds__(128, 4) contract_kernel(
        const float* __restrict__ feat0, const float* __restrict__ feat1,
        const float* __restrict__ feat2,
        const float* __restrict__ sph0,  const float* __restrict__ sph1,
        const float* __restrict__ sph2,
        const float* __restrict__ radial, const float* __restrict__ rbfws,
        float* __restrict__ sparse) {
    __shared__ float radial_s[TTILE * 16];
    __shared__ float sph_s[TTILE * 12];  // [t][0]=sph0, [1..3]=sph1, [4..8]=sph2, [9..11]=pad

    const int f  = threadIdx.x;
    const int t0 = blockIdx.x * TTILE;
    const int n0 = blockIdx.y * NCHUNK;

    float acc[TTILE];
    #pragma unroll
    for (int t = 0; t < TTILE; ++t) acc[t] = 0.0f;

    for (int nn = 0; nn < NCHUNK; ++nn) {
        const int n = n0 + nn;
        // stage radial[n, t0:t0+32, :] (512 contiguous floats)
        {
            const float4* rsrc = reinterpret_cast<const float4*>(radial + ((size_t)n * T_DIM + t0) * 16);
            reinterpret_cast<float4*>(radial_s)[f] = rsrc[f];
        }
        // stage sph: sph0 32 floats, sph1 96, sph2 160
        if (f < 32) sph_s[f * 12 + 0] = sph0[(size_t)n * T_DIM + t0 + f];
        if (f >= 32) {
            const int j = f - 32;  // 0..95
            sph_s[(j / 3) * 12 + 1 + (j % 3)] = sph1[((size_t)n * T_DIM + t0) * 3 + j];
        }
        for (int j = f; j < 160; j += 128)
            sph_s[(j / 5) * 12 + 4 + (j % 5)] = sph2[((size_t)n * T_DIM + t0) * 5 + j];
        __syncthreads();

        // per-thread invariants for this n (all statically indexed -> VGPRs)
        float rb0[16], rb1[16], rb2[16];
        const float* rwsn = rbfws + (size_t)n * 2048 + f;
        #pragma unroll
        for (int r = 0; r < 16; ++r) {
            rb0[r] = rwsn[r * 128];
            rb1[r] = rwsn[262144 + r * 128];
            rb2[r] = rwsn[524288 + r * 128];
        }
        const float f0c = feat0[(size_t)n * F_DIM + f];
        float f1c[3], f2c[5];
        #pragma unroll
        for (int d = 0; d < 3; ++d) f1c[d] = feat1[((size_t)n * F_DIM + f) * 3 + d];
        #pragma unroll
        for (int d = 0; d < 5; ++d) f2c[d] = feat2[((size_t)n * F_DIM + f) * 5 + d];

        #pragma unroll
        for (int t = 0; t < TTILE; ++t) {
            const float4 ra = *reinterpret_cast<const float4*>(&radial_s[t * 16 + 0]);
            const float4 rbv = *reinterpret_cast<const float4*>(&radial_s[t * 16 + 4]);
            const float4 rc = *reinterpret_cast<const float4*>(&radial_s[t * 16 + 8]);
            const float4 rd = *reinterpret_cast<const float4*>(&radial_s[t * 16 + 12]);
            float R0, R1, R2;
            R0 = ra.x * rb0[0];            R1 = ra.x * rb1[0];            R2 = ra.x * rb2[0];
            R0 = fmaf(ra.y, rb0[1], R0);   R1 = fmaf(ra.y, rb1[1], R1);   R2 = fmaf(ra.y, rb2[1], R2);
            R0 = fmaf(ra.z, rb0[2], R0);   R1 = fmaf(ra.z, rb1[2], R1);   R2 = fmaf(ra.z, rb2[2], R2);
            R0 = fmaf(ra.w, rb0[3], R0);   R1 = fmaf(ra.w, rb1[3], R1);   R2 = fmaf(ra.w, rb2[3], R2);
            R0 = fmaf(rbv.x, rb0[4], R0);  R1 = fmaf(rbv.x, rb1[4], R1);  R2 = fmaf(rbv.x, rb2[4], R2);
            R0 = fmaf(rbv.y, rb0[5], R0);  R1 = fmaf(rbv.y, rb1[5], R1);  R2 = fmaf(rbv.y, rb2[5], R2);
            R0 = fmaf(rbv.z, rb0[6], R0);  R1 = fmaf(rbv.z, rb1[6], R1);  R2 = fmaf(rbv.z, rb2[6], R2);
            R0 = fmaf(rbv.w, rb0[7], R0);  R1 = fmaf(rbv.w, rb1[7], R1);  R2 = fmaf(rbv.w, rb2[7], R2);
            R0 = fmaf(rc.x, rb0[8], R0);   R1 = fmaf(rc.x, rb1[8], R1);   R2 = fmaf(rc.x, rb2[8], R2);
            R0 = fmaf(rc.y, rb0[9], R0);   R1 = fmaf(rc.y, rb1[9], R1);   R2 = fmaf(rc.y, rb2[9], R2);
            R0 = fmaf(rc.z, rb0[10], R0);  R1 = fmaf(rc.z, rb1[10], R1);  R2 = fmaf(rc.z, rb2[10], R2);
            R0 = fmaf(rc.w, rb0[11], R0);  R1 = fmaf(rc.w, rb1[11], R1);  R2 = fmaf(rc.w, rb2[11], R2);
            R0 = fmaf(rd.x, rb0[12], R0);  R1 = fmaf(rd.x, rb1[12], R1);  R2 = fmaf(rd.x, rb2[12], R2);
            R0 = fmaf(rd.y, rb0[13], R0);  R1 = fmaf(rd.y, rb1[13], R1);  R2 = fmaf(rd.y, rb2[13], R2);
            R0 = fmaf(rd.z, rb0[14], R0);  R1 = fmaf(rd.z, rb1[14], R1);  R2 = fmaf(rd.z, rb2[14], R2);
            R0 = fmaf(rd.w, rb0[15], R0);  R1 = fmaf(rd.w, rb1[15], R1);  R2 = fmaf(rd.w, rb2[15], R2);

            const float4 sa = *reinterpret_cast<const float4*>(&sph_s[t * 12 + 0]);
            const float4 sb = *reinterpret_cast<const float4*>(&sph_s[t * 12 + 4]);
            const float  s8 = sph_s[t * 12 + 8];
            const float S0 = sa.x * f0c;
            const float S1 = fmaf(sa.y, f1c[0], fmaf(sa.z, f1c[1], sa.w * f1c[2]));
            const float S2 = fmaf(sb.x, f2c[0], fmaf(sb.y, f2c[1],
                             fmaf(sb.z, f2c[2], fmaf(sb.w, f2c[3], s8 * f2c[4]))));
            acc[t] = fmaf(S0, R0, fmaf(S1, R1, fmaf(S2, R2, acc[t])));
        }
        __syncthreads();
    }

    #pragma unroll
    for (int t = 0; t < TTILE; ++t)
        atomicAdd(&sparse[(size_t)(t0 + t) * F_DIM + f], acc[t]);
}

// grid (T/2), block 256: scatter sparse rows into d_out (duplicates via atomics).
__global__ void scatter_kernel(const float* __restrict__ sparse,
                               const int* __restrict__ tidx,
                               float* __restrict__ out) {
    const int tid = threadIdx.x;
    const int t = blockIdx.x * 2 + (tid >> 7);
    const int f = tid & 127;
    const int g = tidx[t];
    atomicAdd(&out[(size_t)g * F_DIM + f], sparse[(size_t)t * F_DIM + f]);
}

extern "C" void kernel_launch(void* const* d_in, const int* in_sizes, int n_in,
                              void* d_out, int out_size, void* d_ws, size_t ws_size,
                              hipStream_t stream) {
    const float* feat0  = (const float*)d_in[0];
    const float* feat1  = (const float*)d_in[1];
    const float* feat2  = (const float*)d_in[2];
    const float* sph0   = (const float*)d_in[3];
    const float* sph1   = (const float*)d_in[4];
    const float* sph2   = (const float*)d_in[5];
    const float* radial = (const float*)d_in[6];
    const float* w1     = (const float*)d_in[7];
    const float* b1     = (const float*)d_in[8];
    const float* w2     = (const float*)d_in[9];
    const float* b2     = (const float*)d_in[10];
    const float* w3     = (const float*)d_in[11];
    const float* b3     = (const float*)d_in[12];
    const int*   tidx   = (const int*)d_in[13];
    float* out = (float*)d_out;

    // workspace: rbf2f (3*128*16*128 f32 = 3 MB) | h2 (3*128*128) | sparse (T*F = 1 MB)
    float* rbfws  = (float*)d_ws;
    float* h2ws   = rbfws + 3 * A_DIM * RBF_DIM * F_DIM;
    float* sparse = h2ws + 3 * A_DIM * F_DIM;

    hipMemsetAsync(d_out, 0, (size_t)out_size * sizeof(float), stream);
    hipMemsetAsync(sparse, 0, (size_t)T_DIM * F_DIM * sizeof(float), stream);

    mlp12_kernel<<<dim3(A_DIM / 4, 3), 512, 0, stream>>>(feat0, w1, b1, w2, b2, h2ws);
    mlp3_kernel<<<dim3(A_DIM / 4, 2, 3), 256, 0, stream>>>(h2ws, w3, b3, rbfws);
    contract_kernel<<<dim3(T_DIM / TTILE, A_DIM / NCHUNK), 128, 0, stream>>>(
        feat0, feat1, feat2, sph0, sph1, sph2, radial, rbfws, sparse);
    scatter_kernel<<<dim3(T_DIM / 2), 256, 0, stream>>>(sparse, tidx, out);
}

// Round 3
// 132.256 us; speedup vs baseline: 1.0558x; 1.0558x over previous
//
#include <hip/hip_runtime.h>
#include <hip/hip_bf16.h>
#include <cstdint>
#include <cstddef>

#define A_DIM 128
#define T_DIM 2048
#define F_DIM 128
#define RBF_DIM 16
#define TTILE 32
#define NCHUNK 4

__device__ __forceinline__ float silu_f(float x) {
    return x / (1.0f + __expf(-x));
}

// grid (A/4, 3), block 512. h1/h2 MLP layers for 4 atoms, one output/thread/layer.
__global__ void mlp12_kernel(const float* __restrict__ feat0,
                             const float* __restrict__ w1, const float* __restrict__ b1,
                             const float* __restrict__ w2, const float* __restrict__ b2,
                             float* __restrict__ h2ws) {
    __shared__ float inv_s[4 * F_DIM];
    __shared__ float h_s[4 * F_DIM];
    const int i  = blockIdx.y;
    const int a0 = blockIdx.x * 4;
    const int tid = threadIdx.x;
    const int f  = tid & 127;
    const int la = tid >> 7;

    inv_s[tid] = feat0[(a0 + la) * F_DIM + f];  // feat0 is (A,F,1)
    __syncthreads();

    const float* w1i = w1 + (size_t)i * F_DIM * F_DIM;
    float x = b1[i * F_DIM + f];
    #pragma unroll 8
    for (int k = 0; k < F_DIM; ++k)
        x = fmaf(inv_s[la * F_DIM + k], w1i[k * F_DIM + f], x);
    h_s[tid] = silu_f(x);
    __syncthreads();

    const float* w2i = w2 + (size_t)i * F_DIM * F_DIM;
    float y = b2[i * F_DIM + f];
    #pragma unroll 8
    for (int k = 0; k < F_DIM; ++k)
        y = fmaf(h_s[la * F_DIM + k], w2i[k * F_DIM + f], y);
    h2ws[((size_t)i * A_DIM + a0 + la) * F_DIM + f] = silu_f(y);
}

// grid (A/4, 2, 3), block 256. Layer 3: (4 atoms)x(1024 cols) tile, 4x4 register tile.
__global__ void mlp3_kernel(const float* __restrict__ h2ws,
                            const float* __restrict__ w3, const float* __restrict__ b3,
                            float* __restrict__ rbfws) {
    __shared__ float h2_s[4 * F_DIM];
    const int i  = blockIdx.z;
    const int a0 = blockIdx.x * 4;
    const int c0 = blockIdx.y * 1024;
    const int tid = threadIdx.x;

    for (int j = tid; j < 4 * F_DIM; j += 256)
        h2_s[j] = h2ws[((size_t)i * A_DIM + a0) * F_DIM + j];
    __syncthreads();

    const int c = c0 + tid * 4;
    const float* w3i = w3 + (size_t)i * F_DIM * 2048;
    float val[4][4];
    #pragma unroll
    for (int a = 0; a < 4; ++a) {
        #pragma unroll
        for (int cc = 0; cc < 4; ++cc)
            val[a][cc] = b3[i * 2048 + c + cc];
    }
    for (int k = 0; k < F_DIM; ++k) {
        const float4 w = *reinterpret_cast<const float4*>(&w3i[(size_t)k * 2048 + c]);
        #pragma unroll
        for (int a = 0; a < 4; ++a) {
            const float h = h2_s[a * F_DIM + k];
            val[a][0] = fmaf(h, w.x, val[a][0]);
            val[a][1] = fmaf(h, w.y, val[a][1]);
            val[a][2] = fmaf(h, w.z, val[a][2]);
            val[a][3] = fmaf(h, w.w, val[a][3]);
        }
    }
    const float inv_rbf = 0.25f;  // 1/sqrt(16)
    #pragma unroll
    for (int a = 0; a < 4; ++a) {
        float4 o;
        o.x = val[a][0] * inv_rbf;
        o.y = val[a][1] * inv_rbf;
        o.z = val[a][2] * inv_rbf;
        o.w = val[a][3] * inv_rbf;
        *reinterpret_cast<float4*>(&rbfws[((size_t)i * A_DIM + a0 + a) * 2048 + c]) = o;
    }
}

// grid (T/32, A/4), block 128 (thread = one f). Factorized einsum, acc into sparse (T,F).
// NOTE: launch_bounds (128,2): min 2 waves/EU -> VGPR cap 256. (128,4) made the
// allocator squeeze to 64 VGPR and spill ~50 regs/thread (R2: 198 MB scratch writes).
__global__ void __launch_bounds__(128, 2) contract_kernel(
        const float* __restrict__ feat0, const float* __restrict__ feat1,
        const float* __restrict__ feat2,
        const float* __restrict__ sph0,  const float* __restrict__ sph1,
        const float* __restrict__ sph2,
        const float* __restrict__ radial, const float* __restrict__ rbfws,
        float* __restrict__ sparse) {
    __shared__ float radial_s[TTILE * 16];
    __shared__ float sph_s[TTILE * 12];  // [t][0]=sph0, [1..3]=sph1, [4..8]=sph2, [9..11]=pad

    const int f  = threadIdx.x;
    const int t0 = blockIdx.x * TTILE;
    const int n0 = blockIdx.y * NCHUNK;

    float acc[TTILE];
    #pragma unroll
    for (int t = 0; t < TTILE; ++t) acc[t] = 0.0f;

    for (int nn = 0; nn < NCHUNK; ++nn) {
        const int n = n0 + nn;
        // stage radial[n, t0:t0+32, :] (512 contiguous floats)
        {
            const float4* rsrc = reinterpret_cast<const float4*>(radial + ((size_t)n * T_DIM + t0) * 16);
            reinterpret_cast<float4*>(radial_s)[f] = rsrc[f];
        }
        // stage sph: sph0 32 floats, sph1 96, sph2 160
        if (f < 32) sph_s[f * 12 + 0] = sph0[(size_t)n * T_DIM + t0 + f];
        if (f >= 32) {
            const int j = f - 32;  // 0..95
            sph_s[(j / 3) * 12 + 1 + (j % 3)] = sph1[((size_t)n * T_DIM + t0) * 3 + j];
        }
        for (int j = f; j < 160; j += 128)
            sph_s[(j / 5) * 12 + 4 + (j % 5)] = sph2[((size_t)n * T_DIM + t0) * 5 + j];
        __syncthreads();

        // per-thread invariants for this n (all statically indexed -> VGPRs)
        float rb0[16], rb1[16], rb2[16];
        const float* rwsn = rbfws + (size_t)n * 2048 + f;
        #pragma unroll
        for (int r = 0; r < 16; ++r) {
            rb0[r] = rwsn[r * 128];
            rb1[r] = rwsn[262144 + r * 128];
            rb2[r] = rwsn[524288 + r * 128];
        }
        const float f0c = feat0[(size_t)n * F_DIM + f];
        float f1c[3], f2c[5];
        #pragma unroll
        for (int d = 0; d < 3; ++d) f1c[d] = feat1[((size_t)n * F_DIM + f) * 3 + d];
        #pragma unroll
        for (int d = 0; d < 5; ++d) f2c[d] = feat2[((size_t)n * F_DIM + f) * 5 + d];

        #pragma unroll
        for (int t = 0; t < TTILE; ++t) {
            const float4 ra = *reinterpret_cast<const float4*>(&radial_s[t * 16 + 0]);
            const float4 rbv = *reinterpret_cast<const float4*>(&radial_s[t * 16 + 4]);
            const float4 rc = *reinterpret_cast<const float4*>(&radial_s[t * 16 + 8]);
            const float4 rd = *reinterpret_cast<const float4*>(&radial_s[t * 16 + 12]);
            float R0, R1, R2;
            R0 = ra.x * rb0[0];            R1 = ra.x * rb1[0];            R2 = ra.x * rb2[0];
            R0 = fmaf(ra.y, rb0[1], R0);   R1 = fmaf(ra.y, rb1[1], R1);   R2 = fmaf(ra.y, rb2[1], R2);
            R0 = fmaf(ra.z, rb0[2], R0);   R1 = fmaf(ra.z, rb1[2], R1);   R2 = fmaf(ra.z, rb2[2], R2);
            R0 = fmaf(ra.w, rb0[3], R0);   R1 = fmaf(ra.w, rb1[3], R1);   R2 = fmaf(ra.w, rb2[3], R2);
            R0 = fmaf(rbv.x, rb0[4], R0);  R1 = fmaf(rbv.x, rb1[4], R1);  R2 = fmaf(rbv.x, rb2[4], R2);
            R0 = fmaf(rbv.y, rb0[5], R0);  R1 = fmaf(rbv.y, rb1[5], R1);  R2 = fmaf(rbv.y, rb2[5], R2);
            R0 = fmaf(rbv.z, rb0[6], R0);  R1 = fmaf(rbv.z, rb1[6], R1);  R2 = fmaf(rbv.z, rb2[6], R2);
            R0 = fmaf(rbv.w, rb0[7], R0);  R1 = fmaf(rbv.w, rb1[7], R1);  R2 = fmaf(rbv.w, rb2[7], R2);
            R0 = fmaf(rc.x, rb0[8], R0);   R1 = fmaf(rc.x, rb1[8], R1);   R2 = fmaf(rc.x, rb2[8], R2);
            R0 = fmaf(rc.y, rb0[9], R0);   R1 = fmaf(rc.y, rb1[9], R1);   R2 = fmaf(rc.y, rb2[9], R2);
            R0 = fmaf(rc.z, rb0[10], R0);  R1 = fmaf(rc.z, rb1[10], R1);  R2 = fmaf(rc.z, rb2[10], R2);
            R0 = fmaf(rc.w, rb0[11], R0);  R1 = fmaf(rc.w, rb1[11], R1);  R2 = fmaf(rc.w, rb2[11], R2);
            R0 = fmaf(rd.x, rb0[12], R0);  R1 = fmaf(rd.x, rb1[12], R1);  R2 = fmaf(rd.x, rb2[12], R2);
            R0 = fmaf(rd.y, rb0[13], R0);  R1 = fmaf(rd.y, rb1[13], R1);  R2 = fmaf(rd.y, rb2[13], R2);
            R0 = fmaf(rd.z, rb0[14], R0);  R1 = fmaf(rd.z, rb1[14], R1);  R2 = fmaf(rd.z, rb2[14], R2);
            R0 = fmaf(rd.w, rb0[15], R0);  R1 = fmaf(rd.w, rb1[15], R1);  R2 = fmaf(rd.w, rb2[15], R2);

            const float4 sa = *reinterpret_cast<const float4*>(&sph_s[t * 12 + 0]);
            const float4 sb = *reinterpret_cast<const float4*>(&sph_s[t * 12 + 4]);
            const float  s8 = sph_s[t * 12 + 8];
            const float S0 = sa.x * f0c;
            const float S1 = fmaf(sa.y, f1c[0], fmaf(sa.z, f1c[1], sa.w * f1c[2]));
            const float S2 = fmaf(sb.x, f2c[0], fmaf(sb.y, f2c[1],
                             fmaf(sb.z, f2c[2], fmaf(sb.w, f2c[3], s8 * f2c[4]))));
            acc[t] = fmaf(S0, R0, fmaf(S1, R1, fmaf(S2, R2, acc[t])));
        }
        __syncthreads();
    }

    #pragma unroll
    for (int t = 0; t < TTILE; ++t)
        atomicAdd(&sparse[(size_t)(t0 + t) * F_DIM + f], acc[t]);
}

// grid (T/2), block 256: scatter sparse rows into d_out (duplicates via atomics).
__global__ void scatter_kernel(const float* __restrict__ sparse,
                               const int* __restrict__ tidx,
                               float* __restrict__ out) {
    const int tid = threadIdx.x;
    const int t = blockIdx.x * 2 + (tid >> 7);
    const int f = tid & 127;
    const int g = tidx[t];
    atomicAdd(&out[(size_t)g * F_DIM + f], sparse[(size_t)t * F_DIM + f]);
}

extern "C" void kernel_launch(void* const* d_in, const int* in_sizes, int n_in,
                              void* d_out, int out_size, void* d_ws, size_t ws_size,
                              hipStream_t stream) {
    const float* feat0  = (const float*)d_in[0];
    const float* feat1  = (const float*)d_in[1];
    const float* feat2  = (const float*)d_in[2];
    const float* sph0   = (const float*)d_in[3];
    const float* sph1   = (const float*)d_in[4];
    const float* sph2   = (const float*)d_in[5];
    const float* radial = (const float*)d_in[6];
    const float* w1     = (const float*)d_in[7];
    const float* b1     = (const float*)d_in[8];
    const float* w2     = (const float*)d_in[9];
    const float* b2     = (const float*)d_in[10];
    const float* w3     = (const float*)d_in[11];
    const float* b3     = (const float*)d_in[12];
    const int*   tidx   = (const int*)d_in[13];
    float* out = (float*)d_out;

    // workspace: rbf2f (3*128*16*128 f32 = 3 MB) | h2 (3*128*128) | sparse (T*F = 1 MB)
    float* rbfws  = (float*)d_ws;
    float* h2ws   = rbfws + 3 * A_DIM * RBF_DIM * F_DIM;
    float* sparse = h2ws + 3 * A_DIM * F_DIM;

    hipMemsetAsync(d_out, 0, (size_t)out_size * sizeof(float), stream);
    hipMemsetAsync(sparse, 0, (size_t)T_DIM * F_DIM * sizeof(float), stream);

    mlp12_kernel<<<dim3(A_DIM / 4, 3), 512, 0, stream>>>(feat0, w1, b1, w2, b2, h2ws);
    mlp3_kernel<<<dim3(A_DIM / 4, 2, 3), 256, 0, stream>>>(h2ws, w3, b3, rbfws);
    contract_kernel<<<dim3(T_DIM / TTILE, A_DIM / NCHUNK), 128, 0, stream>>>(
        feat0, feat1, feat2, sph0, sph1, sph2, radial, rbfws, sparse);
    scatter_kernel<<<dim3(T_DIM / 2), 256, 0, stream>>>(sparse, tidx, out);
}

// Round 4
// 95.861 us; speedup vs baseline: 1.4567x; 1.3797x over previous
//
#include <hip/hip_runtime.h>
#include <hip/hip_bf16.h>
#include <cstdint>
#include <cstddef>

#define A_DIM 128
#define T_DIM 2048
#define F_DIM 128
#define RBF_DIM 16
#define KDD 2048              // K-span per dd block (128 atoms x 16 rbf)
#define VT_LD 18432           // Vt row stride = 9 * KDD

typedef __attribute__((ext_vector_type(8))) short short8;
typedef __attribute__((ext_vector_type(4))) float f32x4;

__device__ __forceinline__ float silu_f(float x) {
    return x / (1.0f + __expf(-x));
}

// f32 -> bf16 bits, round-to-nearest-even
__device__ __forceinline__ unsigned short f2bf(float x) {
    union { float f; unsigned u; } v; v.f = x;
    unsigned r = v.u + 0x7FFFu + ((v.u >> 16) & 1u);
    return (unsigned short)(r >> 16);
}

// grid (A/4, 3), block 512. h1/h2 MLP layers for 4 atoms, one output/thread/layer.
__global__ void mlp12_kernel(const float* __restrict__ feat0,
                             const float* __restrict__ w1, const float* __restrict__ b1,
                             const float* __restrict__ w2, const float* __restrict__ b2,
                             float* __restrict__ h2ws) {
    __shared__ float inv_s[4 * F_DIM];
    __shared__ float h_s[4 * F_DIM];
    const int i  = blockIdx.y;
    const int a0 = blockIdx.x * 4;
    const int tid = threadIdx.x;
    const int f  = tid & 127;
    const int la = tid >> 7;

    inv_s[tid] = feat0[(a0 + la) * F_DIM + f];
    __syncthreads();

    const float* w1i = w1 + (size_t)i * F_DIM * F_DIM;
    float x = b1[i * F_DIM + f];
    #pragma unroll 8
    for (int k = 0; k < F_DIM; ++k)
        x = fmaf(inv_s[la * F_DIM + k], w1i[k * F_DIM + f], x);
    h_s[tid] = silu_f(x);
    __syncthreads();

    const float* w2i = w2 + (size_t)i * F_DIM * F_DIM;
    float y = b2[i * F_DIM + f];
    #pragma unroll 8
    for (int k = 0; k < F_DIM; ++k)
        y = fmaf(h_s[la * F_DIM + k], w2i[k * F_DIM + f], y);
    h2ws[((size_t)i * A_DIM + a0 + la) * F_DIM + f] = silu_f(y);
}

// grid (A/4, 2, 3), block 256. Layer 3: (4 atoms)x(1024 cols) tile, 4x4 register tile.
__global__ void mlp3_kernel(const float* __restrict__ h2ws,
                            const float* __restrict__ w3, const float* __restrict__ b3,
                            float* __restrict__ rbfws) {
    __shared__ float h2_s[4 * F_DIM];
    const int i  = blockIdx.z;
    const int a0 = blockIdx.x * 4;
    const int c0 = blockIdx.y * 1024;
    const int tid = threadIdx.x;

    for (int j = tid; j < 4 * F_DIM; j += 256)
        h2_s[j] = h2ws[((size_t)i * A_DIM + a0) * F_DIM + j];
    __syncthreads();

    const int c = c0 + tid * 4;
    const float* w3i = w3 + (size_t)i * F_DIM * 2048;
    float val[4][4];
    #pragma unroll
    for (int a = 0; a < 4; ++a) {
        #pragma unroll
        for (int cc = 0; cc < 4; ++cc)
            val[a][cc] = b3[i * 2048 + c + cc];
    }
    for (int k = 0; k < F_DIM; ++k) {
        const float4 w = *reinterpret_cast<const float4*>(&w3i[(size_t)k * 2048 + c]);
        #pragma unroll
        for (int a = 0; a < 4; ++a) {
            const float h = h2_s[a * F_DIM + k];
            val[a][0] = fmaf(h, w.x, val[a][0]);
            val[a][1] = fmaf(h, w.y, val[a][1]);
            val[a][2] = fmaf(h, w.z, val[a][2]);
            val[a][3] = fmaf(h, w.w, val[a][3]);
        }
    }
    const float inv_rbf = 0.25f;  // 1/sqrt(16)
    #pragma unroll
    for (int a = 0; a < 4; ++a) {
        float4 o;
        o.x = val[a][0] * inv_rbf;
        o.y = val[a][1] * inv_rbf;
        o.z = val[a][2] * inv_rbf;
        o.w = val[a][3] * inv_rbf;
        *reinterpret_cast<float4*>(&rbfws[((size_t)i * A_DIM + a0 + a) * 2048 + c]) = o;
    }
}

// Build Vt[f][k] bf16, k = dd*2048 + n*16 + r; V = feat_dd[n,f] * rbf2f[i(dd)][n,r,f].
// grid (A, 9), block 128 (thread = f).
__global__ void build_vt_kernel(const float* __restrict__ feat0,
                                const float* __restrict__ feat1,
                                const float* __restrict__ feat2,
                                const float* __restrict__ rbfws,
                                unsigned short* __restrict__ Vt) {
    const int n  = blockIdx.x;
    const int dd = blockIdx.y;
    const int f  = threadIdx.x;

    int i, d;
    float fv;
    if (dd == 0)      { i = 0; d = 0;      fv = feat0[n * F_DIM + f]; }
    else if (dd < 4)  { i = 1; d = dd - 1; fv = feat1[(n * F_DIM + f) * 3 + d]; }
    else              { i = 2; d = dd - 4; fv = feat2[(n * F_DIM + f) * 5 + d]; }

    const float* rb = rbfws + ((size_t)(i * A_DIM + n) * RBF_DIM) * F_DIM + f;
    unsigned short* vp = Vt + (size_t)f * VT_LD + (size_t)dd * KDD + n * 16;
    #pragma unroll
    for (int r = 0; r < RBF_DIM; ++r)
        vp[r] = f2bf(fv * rb[(size_t)r * F_DIM]);
}

// MFMA GEMM: out[t,f] += U[t,k]*V[k,f], U built on the fly (sph*radial), V from Vt.
// grid (16 mt, 32 kg), block 256 = 4 waves in 2x2 (wave tile 64t x 64f).
// k = dd*2048 + n*16 + r ; per block: 4 atoms (K-slice 9 dd x 64).
__global__ void __launch_bounds__(256) gemm_kernel(
        const float* __restrict__ sph0, const float* __restrict__ sph1,
        const float* __restrict__ sph2, const float* __restrict__ radial,
        const unsigned short* __restrict__ Vt,
        float* __restrict__ sparse) {
    const int lane = threadIdx.x & 63;
    const int w    = threadIdx.x >> 6;
    const int wr   = w >> 1;            // wave row (t)
    const int wc   = w & 1;             // wave col (f)
    const int t0   = blockIdx.x * 128 + wr * 64;
    const int n0   = blockIdx.y * 4;
    const int kq   = lane >> 4;         // 0..3
    const int lf   = lane & 15;

    // Per-lane (m,ks) atom/r mapping for A-frags: k_local = 32*ks + 8*kq + j
    //  -> atom na = 2*ks + (kq>>1), r = (kq&1)*8 + j (j contiguous 0..7).
    // radial is dd-invariant: preload once, reuse for all 9 dd.
    f32x4 rad[4][2][2];
    #pragma unroll
    for (int m = 0; m < 4; ++m) {
        const int t = t0 + 16 * m + lf;
        #pragma unroll
        for (int ks = 0; ks < 2; ++ks) {
            const int n = n0 + 2 * ks + (kq >> 1);
            const float* rp = radial + ((size_t)n * T_DIM + t) * 16 + (kq & 1) * 8;
            rad[m][ks][0] = *reinterpret_cast<const f32x4*>(rp);
            rad[m][ks][1] = *reinterpret_cast<const f32x4*>(rp + 4);
        }
    }

    // Vt row base pointers per nf (k part added per dd/ks)
    const unsigned short* vrow[4];
    #pragma unroll
    for (int nf = 0; nf < 4; ++nf) {
        const int f = wc * 64 + 16 * nf + lf;
        vrow[nf] = Vt + (size_t)f * VT_LD + (size_t)n0 * 16 + 8 * kq;
    }

    f32x4 acc[4][4];
    #pragma unroll
    for (int m = 0; m < 4; ++m)
        #pragma unroll
        for (int nf = 0; nf < 4; ++nf)
            acc[m][nf] = (f32x4){0.f, 0.f, 0.f, 0.f};

    #pragma unroll 1
    for (int dd = 0; dd < 9; ++dd) {
        // uniform sph array select
        const float* sp; int smul, soff;
        if (dd == 0)     { sp = sph0; smul = 1; soff = 0; }
        else if (dd < 4) { sp = sph1; smul = 3; soff = dd - 1; }
        else             { sp = sph2; smul = 5; soff = dd - 4; }

        // B-fragments for this dd: [ks][nf]
        short8 b[2][4];
        const size_t koff = (size_t)dd * KDD;
        #pragma unroll
        for (int nf = 0; nf < 4; ++nf) {
            #pragma unroll
            for (int ks = 0; ks < 2; ++ks)
                b[ks][nf] = *reinterpret_cast<const short8*>(vrow[nf] + koff + 32 * ks);
        }

        // A-fragments built in regs, then 16x16x32 MFMAs
        #pragma unroll
        for (int m = 0; m < 4; ++m) {
            const int t = t0 + 16 * m + lf;
            #pragma unroll
            for (int ks = 0; ks < 2; ++ks) {
                const int n = n0 + 2 * ks + (kq >> 1);
                const float s = sp[((size_t)n * T_DIM + t) * smul + soff];
                short8 a;
                #pragma unroll
                for (int j = 0; j < 4; ++j) {
                    a[j]     = (short)f2bf(s * rad[m][ks][0][j]);
                    a[j + 4] = (short)f2bf(s * rad[m][ks][1][j]);
                }
                #pragma unroll
                for (int nf = 0; nf < 4; ++nf)
                    acc[m][nf] = __builtin_amdgcn_mfma_f32_16x16x32_bf16(
                        a, b[ks][nf], acc[m][nf], 0, 0, 0);
            }
        }
    }

    // Epilogue: C/D layout col=lane&15, row=(lane>>4)*4+reg  [measured m89]
    #pragma unroll
    for (int m = 0; m < 4; ++m) {
        #pragma unroll
        for (int nf = 0; nf < 4; ++nf) {
            const int f = wc * 64 + 16 * nf + lf;
            #pragma unroll
            for (int reg = 0; reg < 4; ++reg) {
                const int t = t0 + 16 * m + 4 * kq + reg;
                atomicAdd(&sparse[(size_t)t * F_DIM + f], acc[m][nf][reg]);
            }
        }
    }
}

// grid (T/2), block 256: scatter sparse rows into d_out (duplicates via atomics).
__global__ void scatter_kernel(const float* __restrict__ sparse,
                               const int* __restrict__ tidx,
                               float* __restrict__ out) {
    const int tid = threadIdx.x;
    const int t = blockIdx.x * 2 + (tid >> 7);
    const int f = tid & 127;
    const int g = tidx[t];
    atomicAdd(&out[(size_t)g * F_DIM + f], sparse[(size_t)t * F_DIM + f]);
}

extern "C" void kernel_launch(void* const* d_in, const int* in_sizes, int n_in,
                              void* d_out, int out_size, void* d_ws, size_t ws_size,
                              hipStream_t stream) {
    const float* feat0  = (const float*)d_in[0];
    const float* feat1  = (const float*)d_in[1];
    const float* feat2  = (const float*)d_in[2];
    const float* sph0   = (const float*)d_in[3];
    const float* sph1   = (const float*)d_in[4];
    const float* sph2   = (const float*)d_in[5];
    const float* radial = (const float*)d_in[6];
    const float* w1     = (const float*)d_in[7];
    const float* b1     = (const float*)d_in[8];
    const float* w2     = (const float*)d_in[9];
    const float* b2     = (const float*)d_in[10];
    const float* w3     = (const float*)d_in[11];
    const float* b3     = (const float*)d_in[12];
    const int*   tidx   = (const int*)d_in[13];
    float* out = (float*)d_out;

    // ws: rbfws 3M f32 | h2ws 48K f32 | sparse 256K f32 | Vt 2.36M u16 (~9 MB total)
    float* rbfws  = (float*)d_ws;
    float* h2ws   = rbfws + 3 * A_DIM * RBF_DIM * F_DIM;
    float* sparse = h2ws + 3 * A_DIM * F_DIM;
    unsigned short* Vt = (unsigned short*)(sparse + T_DIM * F_DIM);

    hipMemsetAsync(d_out, 0, (size_t)out_size * sizeof(float), stream);
    hipMemsetAsync(sparse, 0, (size_t)T_DIM * F_DIM * sizeof(float), stream);

    mlp12_kernel<<<dim3(A_DIM / 4, 3), 512, 0, stream>>>(feat0, w1, b1, w2, b2, h2ws);
    mlp3_kernel<<<dim3(A_DIM / 4, 2, 3), 256, 0, stream>>>(h2ws, w3, b3, rbfws);
    build_vt_kernel<<<dim3(A_DIM, 9), 128, 0, stream>>>(feat0, feat1, feat2, rbfws, Vt);
    gemm_kernel<<<dim3(T_DIM / 128, A_DIM / 4), 256, 0, stream>>>(
        sph0, sph1, sph2, radial, Vt, sparse);
    scatter_kernel<<<dim3(T_DIM / 2), 256, 0, stream>>>(sparse, tidx, out);
}

// Round 8
// 78.926 us; speedup vs baseline: 1.7692x; 1.2146x over previous
//
#include <hip/hip_runtime.h>
#include <hip/hip_bf16.h>
#include <cstdint>
#include <cstddef>

#define A_DIM 128
#define T_DIM 2048
#define F_DIM 128
#define RBF_DIM 16
#define KDD 2048              // K-span per dd block (128 atoms x 16 rbf)
#define VT_LD 18432           // Vt row stride = 9 * KDD
#define NKG 32                // K-groups (A_DIM / 4)

typedef __attribute__((ext_vector_type(8))) short short8;
typedef __attribute__((ext_vector_type(4))) float f32x4;

__device__ __forceinline__ float silu_f(float x) {
    return x / (1.0f + __expf(-x));
}

// f32 -> bf16 bits, round-to-nearest-even (known-good from R4; do not swap
// for __float2bfloat16).
__device__ __forceinline__ unsigned short f2bf(float x) {
    union { float f; unsigned u; } v; v.f = x;
    unsigned r = v.u + 0x7FFFu + ((v.u >> 16) & 1u);
    return (unsigned short)(r >> 16);
}

// grid (A/4, 3), block 512. h1/h2 MLP layers for 4 atoms, one output/thread/layer.
__global__ void mlp12_kernel(const float* __restrict__ feat0,
                             const float* __restrict__ w1, const float* __restrict__ b1,
                             const float* __restrict__ w2, const float* __restrict__ b2,
                             float* __restrict__ h2ws) {
    __shared__ float inv_s[4 * F_DIM];
    __shared__ float h_s[4 * F_DIM];
    const int i  = blockIdx.y;
    const int a0 = blockIdx.x * 4;
    const int tid = threadIdx.x;
    const int f  = tid & 127;
    const int la = tid >> 7;

    inv_s[tid] = feat0[(a0 + la) * F_DIM + f];
    __syncthreads();

    const float* w1i = w1 + (size_t)i * F_DIM * F_DIM;
    float x = b1[i * F_DIM + f];
    #pragma unroll 8
    for (int k = 0; k < F_DIM; ++k)
        x = fmaf(inv_s[la * F_DIM + k], w1i[k * F_DIM + f], x);
    h_s[tid] = silu_f(x);
    __syncthreads();

    const float* w2i = w2 + (size_t)i * F_DIM * F_DIM;
    float y = b2[i * F_DIM + f];
    #pragma unroll 8
    for (int k = 0; k < F_DIM; ++k)
        y = fmaf(h_s[la * F_DIM + k], w2i[k * F_DIM + f], y);
    h2ws[((size_t)i * A_DIM + a0 + la) * F_DIM + f] = silu_f(y);
}

// grid (A/4, 2, 3), block 256. Layer 3: (4 atoms)x(1024 cols) tile, 4x4 register tile.
// (R4-exact — known good.)
__global__ void mlp3_kernel(const float* __restrict__ h2ws,
                            const float* __restrict__ w3, const float* __restrict__ b3,
                            float* __restrict__ rbfws) {
    __shared__ float h2_s[4 * F_DIM];
    const int i  = blockIdx.z;
    const int a0 = blockIdx.x * 4;
    const int c0 = blockIdx.y * 1024;
    const int tid = threadIdx.x;

    for (int j = tid; j < 4 * F_DIM; j += 256)
        h2_s[j] = h2ws[((size_t)i * A_DIM + a0) * F_DIM + j];
    __syncthreads();

    const int c = c0 + tid * 4;
    const float* w3i = w3 + (size_t)i * F_DIM * 2048;
    float val[4][4];
    #pragma unroll
    for (int a = 0; a < 4; ++a) {
        #pragma unroll
        for (int cc = 0; cc < 4; ++cc)
            val[a][cc] = b3[i * 2048 + c + cc];
    }
    for (int k = 0; k < F_DIM; ++k) {
        const float4 w = *reinterpret_cast<const float4*>(&w3i[(size_t)k * 2048 + c]);
        #pragma unroll
        for (int a = 0; a < 4; ++a) {
            const float h = h2_s[a * F_DIM + k];
            val[a][0] = fmaf(h, w.x, val[a][0]);
            val[a][1] = fmaf(h, w.y, val[a][1]);
            val[a][2] = fmaf(h, w.z, val[a][2]);
            val[a][3] = fmaf(h, w.w, val[a][3]);
        }
    }
    const float inv_rbf = 0.25f;  // 1/sqrt(16)
    #pragma unroll
    for (int a = 0; a < 4; ++a) {
        float4 o;
        o.x = val[a][0] * inv_rbf;
        o.y = val[a][1] * inv_rbf;
        o.z = val[a][2] * inv_rbf;
        o.w = val[a][3] * inv_rbf;
        *reinterpret_cast<float4*>(&rbfws[((size_t)i * A_DIM + a0 + a) * 2048 + c]) = o;
    }
}

// Build Vt[f][k] bf16, k = dd*2048 + n*16 + r. (R4-exact.)
__global__ void build_vt_kernel(const float* __restrict__ feat0,
                                const float* __restrict__ feat1,
                                const float* __restrict__ feat2,
                                const float* __restrict__ rbfws,
                                unsigned short* __restrict__ Vt) {
    const int n  = blockIdx.x;
    const int dd = blockIdx.y;
    const int f  = threadIdx.x;

    int i, d;
    float fv;
    if (dd == 0)      { i = 0; d = 0;      fv = feat0[n * F_DIM + f]; }
    else if (dd < 4)  { i = 1; d = dd - 1; fv = feat1[(n * F_DIM + f) * 3 + d]; }
    else              { i = 2; d = dd - 4; fv = feat2[(n * F_DIM + f) * 5 + d]; }

    const float* rb = rbfws + ((size_t)(i * A_DIM + n) * RBF_DIM) * F_DIM + f;
    unsigned short* vp = Vt + (size_t)f * VT_LD + (size_t)dd * KDD + n * 16;
    #pragma unroll
    for (int r = 0; r < RBF_DIM; ++r)
        vp[r] = f2bf(fv * rb[(size_t)r * F_DIM]);
}

// MFMA GEMM — R4-exact body (monolithic dd-loop, #pragma unroll 1). The ONLY
// change vs R4 is the epilogue: MODE 0 plain-stores this K-group's partial
// tile to its own 1 MB slice (no contention); MODE 1 = R4's atomicAdd path.
// grid (16 mt, 32 kg), block 256 = 4 waves in 2x2 (wave tile 64t x 64f).
// k = dd*2048 + n*16 + r ; per block: 4 atoms (K-slice 9 dd x 64).
template<int MODE>
__global__ void __launch_bounds__(256) gemm_kernel(
        const float* __restrict__ sph0, const float* __restrict__ sph1,
        const float* __restrict__ sph2, const float* __restrict__ radial,
        const unsigned short* __restrict__ Vt,
        float* __restrict__ outbuf) {
    const int lane = threadIdx.x & 63;
    const int w    = threadIdx.x >> 6;
    const int wr   = w >> 1;            // wave row (t)
    const int wc   = w & 1;             // wave col (f)
    const int t0   = blockIdx.x * 128 + wr * 64;
    const int n0   = blockIdx.y * 4;
    const int kq   = lane >> 4;         // 0..3
    const int lf   = lane & 15;

    // Per-lane (m,ks) atom/r mapping for A-frags: k_local = 32*ks + 8*kq + j
    //  -> atom na = 2*ks + (kq>>1), r = (kq&1)*8 + j (j contiguous 0..7).
    // radial is dd-invariant: preload once, reuse for all 9 dd.
    f32x4 rad[4][2][2];
    #pragma unroll
    for (int m = 0; m < 4; ++m) {
        const int t = t0 + 16 * m + lf;
        #pragma unroll
        for (int ks = 0; ks < 2; ++ks) {
            const int n = n0 + 2 * ks + (kq >> 1);
            const float* rp = radial + ((size_t)n * T_DIM + t) * 16 + (kq & 1) * 8;
            rad[m][ks][0] = *reinterpret_cast<const f32x4*>(rp);
            rad[m][ks][1] = *reinterpret_cast<const f32x4*>(rp + 4);
        }
    }

    // Vt row base pointers per nf (k part added per dd/ks)
    const unsigned short* vrow[4];
    #pragma unroll
    for (int nf = 0; nf < 4; ++nf) {
        const int f = wc * 64 + 16 * nf + lf;
        vrow[nf] = Vt + (size_t)f * VT_LD + (size_t)n0 * 16 + 8 * kq;
    }

    f32x4 acc[4][4];
    #pragma unroll
    for (int m = 0; m < 4; ++m)
        #pragma unroll
        for (int nf = 0; nf < 4; ++nf)
            acc[m][nf] = (f32x4){0.f, 0.f, 0.f, 0.f};

    #pragma unroll 1
    for (int dd = 0; dd < 9; ++dd) {
        // uniform sph array select
        const float* sp; int smul, soff;
        if (dd == 0)     { sp = sph0; smul = 1; soff = 0; }
        else if (dd < 4) { sp = sph1; smul = 3; soff = dd - 1; }
        else             { sp = sph2; smul = 5; soff = dd - 4; }

        // B-fragments for this dd: [ks][nf]
        short8 b[2][4];
        const size_t koff = (size_t)dd * KDD;
        #pragma unroll
        for (int nf = 0; nf < 4; ++nf) {
            #pragma unroll
            for (int ks = 0; ks < 2; ++ks)
                b[ks][nf] = *reinterpret_cast<const short8*>(vrow[nf] + koff + 32 * ks);
        }

        // A-fragments built in regs, then 16x16x32 MFMAs
        #pragma unroll
        for (int m = 0; m < 4; ++m) {
            const int t = t0 + 16 * m + lf;
            #pragma unroll
            for (int ks = 0; ks < 2; ++ks) {
                const int n = n0 + 2 * ks + (kq >> 1);
                const float s = sp[((size_t)n * T_DIM + t) * smul + soff];
                short8 a;
                #pragma unroll
                for (int j = 0; j < 4; ++j) {
                    a[j]     = (short)f2bf(s * rad[m][ks][0][j]);
                    a[j + 4] = (short)f2bf(s * rad[m][ks][1][j]);
                }
                #pragma unroll
                for (int nf = 0; nf < 4; ++nf)
                    acc[m][nf] = __builtin_amdgcn_mfma_f32_16x16x32_bf16(
                        a, b[ks][nf], acc[m][nf], 0, 0, 0);
            }
        }
    }

    // Epilogue. C/D layout col=lane&15, row=(lane>>4)*4+reg (HW-verified in R4).
    float* pb = (MODE == 0)
        ? outbuf + (size_t)blockIdx.y * (T_DIM * F_DIM)   // own slice, plain stores
        : outbuf;                                          // shared, atomics
    #pragma unroll
    for (int m = 0; m < 4; ++m) {
        #pragma unroll
        for (int nf = 0; nf < 4; ++nf) {
            const int f = wc * 64 + 16 * nf + lf;
            #pragma unroll
            for (int reg = 0; reg < 4; ++reg) {
                const int t = t0 + 16 * m + 4 * kq + reg;
                if (MODE == 0)
                    pb[(size_t)t * F_DIM + f] = acc[m][nf][reg];
                else
                    atomicAdd(&pb[(size_t)t * F_DIM + f], acc[m][nf][reg]);
            }
        }
    }
}

// Plain path: sum 32 partial slices, then indexed atomicAdd into out.
// grid (T/2), block 256.
__global__ void scatter_sum_kernel(const float* __restrict__ partial,
                                   const int* __restrict__ tidx,
                                   float* __restrict__ out) {
    const int tid = threadIdx.x;
    const int t = blockIdx.x * 2 + (tid >> 7);
    const int f = tid & 127;
    const int g = tidx[t];
    const float* p = partial + (size_t)t * F_DIM + f;
    float s = 0.0f;
    #pragma unroll
    for (int kg = 0; kg < NKG; ++kg)
        s += p[(size_t)kg * (T_DIM * F_DIM)];
    atomicAdd(&out[(size_t)g * F_DIM + f], s);
}

// Fallback path (R4-exact): scatter sparse rows into d_out.
__global__ void scatter_kernel(const float* __restrict__ sparse,
                               const int* __restrict__ tidx,
                               float* __restrict__ out) {
    const int tid = threadIdx.x;
    const int t = blockIdx.x * 2 + (tid >> 7);
    const int f = tid & 127;
    const int g = tidx[t];
    atomicAdd(&out[(size_t)g * F_DIM + f], sparse[(size_t)t * F_DIM + f]);
}

extern "C" void kernel_launch(void* const* d_in, const int* in_sizes, int n_in,
                              void* d_out, int out_size, void* d_ws, size_t ws_size,
                              hipStream_t stream) {
    const float* feat0  = (const float*)d_in[0];
    const float* feat1  = (const float*)d_in[1];
    const float* feat2  = (const float*)d_in[2];
    const float* sph0   = (const float*)d_in[3];
    const float* sph1   = (const float*)d_in[4];
    const float* sph2   = (const float*)d_in[5];
    const float* radial = (const float*)d_in[6];
    const float* w1     = (const float*)d_in[7];
    const float* b1     = (const float*)d_in[8];
    const float* w2     = (const float*)d_in[9];
    const float* b2     = (const float*)d_in[10];
    const float* w3     = (const float*)d_in[11];
    const float* b3     = (const float*)d_in[12];
    const int*   tidx   = (const int*)d_in[13];
    float* out = (float*)d_out;

    // Common ws prefix: rbfws 3 MB | h2ws 192 KB
    float* rbfws  = (float*)d_ws;
    float* h2ws   = rbfws + 3 * A_DIM * RBF_DIM * F_DIM;

    // Plain path needs: prefix + Vt (4.5 MB) + partial (32 MB) ~= 41.7 MB
    const size_t plain_need =
        (size_t)(3 * A_DIM * RBF_DIM * F_DIM + 3 * A_DIM * F_DIM) * sizeof(float) +
        (size_t)F_DIM * VT_LD * sizeof(unsigned short) +
        (size_t)NKG * T_DIM * F_DIM * sizeof(float);
    const bool plain = (ws_size >= plain_need);

    hipMemsetAsync(d_out, 0, (size_t)out_size * sizeof(float), stream);

    mlp12_kernel<<<dim3(A_DIM / 4, 3), 512, 0, stream>>>(feat0, w1, b1, w2, b2, h2ws);
    mlp3_kernel<<<dim3(A_DIM / 4, 2, 3), 256, 0, stream>>>(h2ws, w3, b3, rbfws);

    if (plain) {
        unsigned short* Vt = (unsigned short*)(h2ws + 3 * A_DIM * F_DIM);
        float* partial = (float*)(Vt + (size_t)F_DIM * VT_LD);
        build_vt_kernel<<<dim3(A_DIM, 9), 128, 0, stream>>>(feat0, feat1, feat2, rbfws, Vt);
        gemm_kernel<0><<<dim3(T_DIM / 128, A_DIM / 4), 256, 0, stream>>>(
            sph0, sph1, sph2, radial, Vt, partial);
        scatter_sum_kernel<<<dim3(T_DIM / 2), 256, 0, stream>>>(partial, tidx, out);
    } else {
        // R4-exact fallback layout: rbfws | h2ws | sparse | Vt
        float* sparse = h2ws + 3 * A_DIM * F_DIM;
        unsigned short* Vt = (unsigned short*)(sparse + T_DIM * F_DIM);
        hipMemsetAsync(sparse, 0, (size_t)T_DIM * F_DIM * sizeof(float), stream);
        build_vt_kernel<<<dim3(A_DIM, 9), 128, 0, stream>>>(feat0, feat1, feat2, rbfws, Vt);
        gemm_kernel<1><<<dim3(T_DIM / 128, A_DIM / 4), 256, 0, stream>>>(
            sph0, sph1, sph2, radial, Vt, sparse);
        scatter_kernel<<<dim3(T_DIM / 2), 256, 0, stream>>>(sparse, tidx, out);
    }
}

// Round 9
// 78.141 us; speedup vs baseline: 1.7870x; 1.0100x over previous
//
#include <hip/hip_runtime.h>
#include <hip/hip_bf16.h>
#include <cstdint>
#include <cstddef>

#define A_DIM 128
#define T_DIM 2048
#define F_DIM 128
#define RBF_DIM 16
#define KDD 2048              // K-span per dd block (128 atoms x 16 rbf)
#define VT_LD 18432           // Vt row stride = 9 * KDD
#define NKG 32                // K-groups (A_DIM / 4)

typedef __attribute__((ext_vector_type(8))) short short8;
typedef __attribute__((ext_vector_type(4))) float f32x4;

__device__ __forceinline__ float silu_f(float x) {
    return x / (1.0f + __expf(-x));
}

// f32 -> bf16 bits, round-to-nearest-even (known-good from R4; do not swap
// for __float2bfloat16).
__device__ __forceinline__ unsigned short f2bf(float x) {
    union { float f; unsigned u; } v; v.f = x;
    unsigned r = v.u + 0x7FFFu + ((v.u >> 16) & 1u);
    return (unsigned short)(r >> 16);
}

// Custom zero-fill: hipMemsetAsync's fillBufferAligned ran at 777 GB/s
// (43 us for 33.5 MB — 55% of total runtime in R8). Grid-stride float4
// stores hit ~6 TB/s.
__global__ void zero_kernel(float4* __restrict__ p, int n4) {
    const int stride = gridDim.x * blockDim.x;
    const float4 z = {0.f, 0.f, 0.f, 0.f};
    for (int i = blockIdx.x * blockDim.x + threadIdx.x; i < n4; i += stride)
        p[i] = z;
}

// grid (A/4, 3), block 512. h1/h2 MLP layers for 4 atoms, one output/thread/layer.
__global__ void mlp12_kernel(const float* __restrict__ feat0,
                             const float* __restrict__ w1, const float* __restrict__ b1,
                             const float* __restrict__ w2, const float* __restrict__ b2,
                             float* __restrict__ h2ws) {
    __shared__ float inv_s[4 * F_DIM];
    __shared__ float h_s[4 * F_DIM];
    const int i  = blockIdx.y;
    const int a0 = blockIdx.x * 4;
    const int tid = threadIdx.x;
    const int f  = tid & 127;
    const int la = tid >> 7;

    inv_s[tid] = feat0[(a0 + la) * F_DIM + f];
    __syncthreads();

    const float* w1i = w1 + (size_t)i * F_DIM * F_DIM;
    float x = b1[i * F_DIM + f];
    #pragma unroll 8
    for (int k = 0; k < F_DIM; ++k)
        x = fmaf(inv_s[la * F_DIM + k], w1i[k * F_DIM + f], x);
    h_s[tid] = silu_f(x);
    __syncthreads();

    const float* w2i = w2 + (size_t)i * F_DIM * F_DIM;
    float y = b2[i * F_DIM + f];
    #pragma unroll 8
    for (int k = 0; k < F_DIM; ++k)
        y = fmaf(h_s[la * F_DIM + k], w2i[k * F_DIM + f], y);
    h2ws[((size_t)i * A_DIM + a0 + la) * F_DIM + f] = silu_f(y);
}

// grid (A/4, 2, 3), block 256. Layer 3: (4 atoms)x(1024 cols) tile, 4x4 register tile.
// (R4-exact — known good.)
__global__ void mlp3_kernel(const float* __restrict__ h2ws,
                            const float* __restrict__ w3, const float* __restrict__ b3,
                            float* __restrict__ rbfws) {
    __shared__ float h2_s[4 * F_DIM];
    const int i  = blockIdx.z;
    const int a0 = blockIdx.x * 4;
    const int c0 = blockIdx.y * 1024;
    const int tid = threadIdx.x;

    for (int j = tid; j < 4 * F_DIM; j += 256)
        h2_s[j] = h2ws[((size_t)i * A_DIM + a0) * F_DIM + j];
    __syncthreads();

    const int c = c0 + tid * 4;
    const float* w3i = w3 + (size_t)i * F_DIM * 2048;
    float val[4][4];
    #pragma unroll
    for (int a = 0; a < 4; ++a) {
        #pragma unroll
        for (int cc = 0; cc < 4; ++cc)
            val[a][cc] = b3[i * 2048 + c + cc];
    }
    for (int k = 0; k < F_DIM; ++k) {
        const float4 w = *reinterpret_cast<const float4*>(&w3i[(size_t)k * 2048 + c]);
        #pragma unroll
        for (int a = 0; a < 4; ++a) {
            const float h = h2_s[a * F_DIM + k];
            val[a][0] = fmaf(h, w.x, val[a][0]);
            val[a][1] = fmaf(h, w.y, val[a][1]);
            val[a][2] = fmaf(h, w.z, val[a][2]);
            val[a][3] = fmaf(h, w.w, val[a][3]);
        }
    }
    const float inv_rbf = 0.25f;  // 1/sqrt(16)
    #pragma unroll
    for (int a = 0; a < 4; ++a) {
        float4 o;
        o.x = val[a][0] * inv_rbf;
        o.y = val[a][1] * inv_rbf;
        o.z = val[a][2] * inv_rbf;
        o.w = val[a][3] * inv_rbf;
        *reinterpret_cast<float4*>(&rbfws[((size_t)i * A_DIM + a0 + a) * 2048 + c]) = o;
    }
}

// Build Vt[f][k] bf16, k = dd*2048 + n*16 + r. (R4-exact.)
__global__ void build_vt_kernel(const float* __restrict__ feat0,
                                const float* __restrict__ feat1,
                                const float* __restrict__ feat2,
                                const float* __restrict__ rbfws,
                                unsigned short* __restrict__ Vt) {
    const int n  = blockIdx.x;
    const int dd = blockIdx.y;
    const int f  = threadIdx.x;

    int i, d;
    float fv;
    if (dd == 0)      { i = 0; d = 0;      fv = feat0[n * F_DIM + f]; }
    else if (dd < 4)  { i = 1; d = dd - 1; fv = feat1[(n * F_DIM + f) * 3 + d]; }
    else              { i = 2; d = dd - 4; fv = feat2[(n * F_DIM + f) * 5 + d]; }

    const float* rb = rbfws + ((size_t)(i * A_DIM + n) * RBF_DIM) * F_DIM + f;
    unsigned short* vp = Vt + (size_t)f * VT_LD + (size_t)dd * KDD + n * 16;
    #pragma unroll
    for (int r = 0; r < RBF_DIM; ++r)
        vp[r] = f2bf(fv * rb[(size_t)r * F_DIM]);
}

// MFMA GEMM — R4-exact body (monolithic dd-loop, #pragma unroll 1). MODE 0
// plain-stores this K-group's partial tile to its own slice; MODE 1 = atomics.
// grid (16 mt, 32 kg), block 256 = 4 waves in 2x2 (wave tile 64t x 64f).
// k = dd*2048 + n*16 + r ; per block: 4 atoms (K-slice 9 dd x 64).
template<int MODE>
__global__ void __launch_bounds__(256) gemm_kernel(
        const float* __restrict__ sph0, const float* __restrict__ sph1,
        const float* __restrict__ sph2, const float* __restrict__ radial,
        const unsigned short* __restrict__ Vt,
        float* __restrict__ outbuf) {
    const int lane = threadIdx.x & 63;
    const int w    = threadIdx.x >> 6;
    const int wr   = w >> 1;            // wave row (t)
    const int wc   = w & 1;             // wave col (f)
    const int t0   = blockIdx.x * 128 + wr * 64;
    const int n0   = blockIdx.y * 4;
    const int kq   = lane >> 4;         // 0..3
    const int lf   = lane & 15;

    // Per-lane (m,ks) atom/r mapping for A-frags: k_local = 32*ks + 8*kq + j
    //  -> atom na = 2*ks + (kq>>1), r = (kq&1)*8 + j (j contiguous 0..7).
    // radial is dd-invariant: preload once, reuse for all 9 dd.
    f32x4 rad[4][2][2];
    #pragma unroll
    for (int m = 0; m < 4; ++m) {
        const int t = t0 + 16 * m + lf;
        #pragma unroll
        for (int ks = 0; ks < 2; ++ks) {
            const int n = n0 + 2 * ks + (kq >> 1);
            const float* rp = radial + ((size_t)n * T_DIM + t) * 16 + (kq & 1) * 8;
            rad[m][ks][0] = *reinterpret_cast<const f32x4*>(rp);
            rad[m][ks][1] = *reinterpret_cast<const f32x4*>(rp + 4);
        }
    }

    // Vt row base pointers per nf (k part added per dd/ks)
    const unsigned short* vrow[4];
    #pragma unroll
    for (int nf = 0; nf < 4; ++nf) {
        const int f = wc * 64 + 16 * nf + lf;
        vrow[nf] = Vt + (size_t)f * VT_LD + (size_t)n0 * 16 + 8 * kq;
    }

    f32x4 acc[4][4];
    #pragma unroll
    for (int m = 0; m < 4; ++m)
        #pragma unroll
        for (int nf = 0; nf < 4; ++nf)
            acc[m][nf] = (f32x4){0.f, 0.f, 0.f, 0.f};

    #pragma unroll 1
    for (int dd = 0; dd < 9; ++dd) {
        // uniform sph array select
        const float* sp; int smul, soff;
        if (dd == 0)     { sp = sph0; smul = 1; soff = 0; }
        else if (dd < 4) { sp = sph1; smul = 3; soff = dd - 1; }
        else             { sp = sph2; smul = 5; soff = dd - 4; }

        // B-fragments for this dd: [ks][nf]
        short8 b[2][4];
        const size_t koff = (size_t)dd * KDD;
        #pragma unroll
        for (int nf = 0; nf < 4; ++nf) {
            #pragma unroll
            for (int ks = 0; ks < 2; ++ks)
                b[ks][nf] = *reinterpret_cast<const short8*>(vrow[nf] + koff + 32 * ks);
        }

        // A-fragments built in regs, then 16x16x32 MFMAs
        #pragma unroll
        for (int m = 0; m < 4; ++m) {
            const int t = t0 + 16 * m + lf;
            #pragma unroll
            for (int ks = 0; ks < 2; ++ks) {
                const int n = n0 + 2 * ks + (kq >> 1);
                const float s = sp[((size_t)n * T_DIM + t) * smul + soff];
                short8 a;
                #pragma unroll
                for (int j = 0; j < 4; ++j) {
                    a[j]     = (short)f2bf(s * rad[m][ks][0][j]);
                    a[j + 4] = (short)f2bf(s * rad[m][ks][1][j]);
                }
                #pragma unroll
                for (int nf = 0; nf < 4; ++nf)
                    acc[m][nf] = __builtin_amdgcn_mfma_f32_16x16x32_bf16(
                        a, b[ks][nf], acc[m][nf], 0, 0, 0);
            }
        }
    }

    // Epilogue. C/D layout col=lane&15, row=(lane>>4)*4+reg (HW-verified in R4).
    float* pb = (MODE == 0)
        ? outbuf + (size_t)blockIdx.y * (T_DIM * F_DIM)   // own slice, plain stores
        : outbuf;                                          // shared, atomics
    #pragma unroll
    for (int m = 0; m < 4; ++m) {
        #pragma unroll
        for (int nf = 0; nf < 4; ++nf) {
            const int f = wc * 64 + 16 * nf + lf;
            #pragma unroll
            for (int reg = 0; reg < 4; ++reg) {
                const int t = t0 + 16 * m + 4 * kq + reg;
                if (MODE == 0)
                    pb[(size_t)t * F_DIM + f] = acc[m][nf][reg];
                else
                    atomicAdd(&pb[(size_t)t * F_DIM + f], acc[m][nf][reg]);
            }
        }
    }
}

// Plain path: sum 32 partial slices, then indexed atomicAdd into out.
// grid (T/2), block 256.
__global__ void scatter_sum_kernel(const float* __restrict__ partial,
                                   const int* __restrict__ tidx,
                                   float* __restrict__ out) {
    const int tid = threadIdx.x;
    const int t = blockIdx.x * 2 + (tid >> 7);
    const int f = tid & 127;
    const int g = tidx[t];
    const float* p = partial + (size_t)t * F_DIM + f;
    float s = 0.0f;
    #pragma unroll
    for (int kg = 0; kg < NKG; ++kg)
        s += p[(size_t)kg * (T_DIM * F_DIM)];
    atomicAdd(&out[(size_t)g * F_DIM + f], s);
}

// Fallback path (R4-exact): scatter sparse rows into d_out.
__global__ void scatter_kernel(const float* __restrict__ sparse,
                               const int* __restrict__ tidx,
                               float* __restrict__ out) {
    const int tid = threadIdx.x;
    const int t = blockIdx.x * 2 + (tid >> 7);
    const int f = tid & 127;
    const int g = tidx[t];
    atomicAdd(&out[(size_t)g * F_DIM + f], sparse[(size_t)t * F_DIM + f]);
}

extern "C" void kernel_launch(void* const* d_in, const int* in_sizes, int n_in,
                              void* d_out, int out_size, void* d_ws, size_t ws_size,
                              hipStream_t stream) {
    const float* feat0  = (const float*)d_in[0];
    const float* feat1  = (const float*)d_in[1];
    const float* feat2  = (const float*)d_in[2];
    const float* sph0   = (const float*)d_in[3];
    const float* sph1   = (const float*)d_in[4];
    const float* sph2   = (const float*)d_in[5];
    const float* radial = (const float*)d_in[6];
    const float* w1     = (const float*)d_in[7];
    const float* b1     = (const float*)d_in[8];
    const float* w2     = (const float*)d_in[9];
    const float* b2     = (const float*)d_in[10];
    const float* w3     = (const float*)d_in[11];
    const float* b3     = (const float*)d_in[12];
    const int*   tidx   = (const int*)d_in[13];
    float* out = (float*)d_out;

    // Common ws prefix: rbfws 3 MB | h2ws 192 KB
    float* rbfws  = (float*)d_ws;
    float* h2ws   = rbfws + 3 * A_DIM * RBF_DIM * F_DIM;

    // Plain path needs: prefix + Vt (4.5 MB) + partial (32 MB) ~= 41.7 MB
    const size_t plain_need =
        (size_t)(3 * A_DIM * RBF_DIM * F_DIM + 3 * A_DIM * F_DIM) * sizeof(float) +
        (size_t)F_DIM * VT_LD * sizeof(unsigned short) +
        (size_t)NKG * T_DIM * F_DIM * sizeof(float);
    const bool plain = (ws_size >= plain_need);

    // Custom zero of d_out (runtime fillBuffer ran at 777 GB/s = 43 us).
    zero_kernel<<<2048, 256, 0, stream>>>((float4*)out, out_size / 4);

    mlp12_kernel<<<dim3(A_DIM / 4, 3), 512, 0, stream>>>(feat0, w1, b1, w2, b2, h2ws);
    mlp3_kernel<<<dim3(A_DIM / 4, 2, 3), 256, 0, stream>>>(h2ws, w3, b3, rbfws);

    if (plain) {
        unsigned short* Vt = (unsigned short*)(h2ws + 3 * A_DIM * F_DIM);
        float* partial = (float*)(Vt + (size_t)F_DIM * VT_LD);
        build_vt_kernel<<<dim3(A_DIM, 9), 128, 0, stream>>>(feat0, feat1, feat2, rbfws, Vt);
        gemm_kernel<0><<<dim3(T_DIM / 128, A_DIM / 4), 256, 0, stream>>>(
            sph0, sph1, sph2, radial, Vt, partial);
        scatter_sum_kernel<<<dim3(T_DIM / 2), 256, 0, stream>>>(partial, tidx, out);
    } else {
        // R4-exact fallback layout: rbfws | h2ws | sparse | Vt
        float* sparse = h2ws + 3 * A_DIM * F_DIM;
        unsigned short* Vt = (unsigned short*)(sparse + T_DIM * F_DIM);
        hipMemsetAsync(sparse, 0, (size_t)T_DIM * F_DIM * sizeof(float), stream);
        build_vt_kernel<<<dim3(A_DIM, 9), 128, 0, stream>>>(feat0, feat1, feat2, rbfws, Vt);
        gemm_kernel<1><<<dim3(T_DIM / 128, A_DIM / 4), 256, 0, stream>>>(
            sph0, sph1, sph2, radial, Vt, sparse);
        scatter_kernel<<<dim3(T_DIM / 2), 256, 0, stream>>>(sparse, tidx, out);
    }
}